// Round 1
// baseline (1686.477 us; speedup 1.0000x reference)
//
#include <hip/hip_runtime.h>
#include <stdint.h>

#define KPS 512
#define NBOX 1536
#define NBINS 4096

// scale cell counts: 32*H*H*3
#define S13 16224
#define S26 64896
#define S52 259584
#define TOTCELL 340704

// candidate segment bases/caps (in keys)
#define C13_BASE 0
#define C26_BASE 16384
#define C52_BASE 81920
#define CAND_CAP 344064

__device__ __forceinline__ uint32_t f2u(float x){ union{float f;uint32_t u;}v; v.f=x; return v.u; }
__device__ __forceinline__ float u2f(uint32_t x){ union{float f;uint32_t u;}v; v.u=x; return v.f; }

__device__ __forceinline__ int binOf(float s){
    int b = (int)((s - 0.6f) * 10240.0f);
    if (b < 0) b = 0;
    if (b > NBINS-1) b = NBINS-1;
    return b;
}

// counters: [0..2] candCnt, [3..5] abovePos, [6..8] stashCnt, [9..11] cutoffB, [12..14] aboveCount
__global__ void k_init(int* hist, int* cnt){
    int id = blockIdx.x*256 + threadIdx.x;
    if (id < 3*NBINS) hist[id] = 0;
    if (id < 32) cnt[id] = 0;
}

__global__ void k_score(const float* __restrict__ o13, const float* __restrict__ o26,
                        const float* __restrict__ o52,
                        unsigned long long* __restrict__ cand, int* __restrict__ cnt,
                        int* __restrict__ hist){
    int id = blockIdx.x*256 + threadIdx.x;
    if (id >= TOTCELL) return;
    int scale, idl, H, segbase;
    const float* src;
    if (id < S13)            { scale=0; idl=id;            H=13; src=o13; segbase=C13_BASE; }
    else if (id < S13+S26)   { scale=1; idl=id-S13;        H=26; src=o26; segbase=C26_BASE; }
    else                     { scale=2; idl=id-(S13+S26);  H=52; src=o52; segbase=C52_BASE; }
    int HW = H*H;
    // plane-major thread mapping for coalescing: idl = p*HW + hw, p = n*3 + a
    int p  = idl / HW;
    int hw = idl - p*HW;
    int n  = p / 3;
    int a  = p - n*3;
    int cidx = (n*HW + hw)*3 + a;       // reference flat cell index
    float x = src[(size_t)(n*255 + a*85)*HW + hw];
    float s = (float)(1.0 / (1.0 + exp(-(double)x)));   // correctly-rounded f32 sigmoid
    if (s > 0.6f){
        atomicAdd(&hist[scale*NBINS + binOf(s)], 1);
        int pos = atomicAdd(&cnt[scale], 1);
        unsigned long long key = ((unsigned long long)f2u(s) << 20)
                               | ((unsigned long long)(2-scale) << 18)
                               | (unsigned long long)(262143 - cidx);
        cand[segbase + pos] = key;
    }
}

__global__ void __launch_bounds__(1024) k_cutoff(const int* __restrict__ hist, int* __restrict__ cnt){
    int s = blockIdx.x, t = threadIdx.x;
    __shared__ int h[NBINS];
    __shared__ int suf[1024];
    #pragma unroll
    for (int k=0;k<4;k++) h[t*4+k] = hist[s*NBINS + t*4 + k];
    __syncthreads();
    int part = h[4*t] + h[4*t+1] + h[4*t+2] + h[4*t+3];
    suf[t] = part; __syncthreads();
    for (int d=1; d<1024; d<<=1){
        int v = (t+d < 1024) ? suf[t+d] : 0;
        __syncthreads();
        suf[t] += v;
        __syncthreads();
    }
    int total = suf[0];
    int A = (t < 1023) ? suf[t+1] : 0;
    int ca3 = A;
    int ca2 = A   + h[4*t+3];
    int ca1 = ca2 + h[4*t+2];
    int ca0 = ca1 + h[4*t+1];
    int ca[4] = {ca0, ca1, ca2, ca3};
    if (t == 0 && total < KPS){ cnt[9+s] = -1; cnt[12+s] = total; }
    #pragma unroll
    for (int k=0;k<4;k++){
        int b = 4*t + k;
        if (ca[k] < KPS && ca[k] + h[b] >= KPS){ cnt[9+s] = b; cnt[12+s] = ca[k]; }
    }
}

__global__ void k_classify(const unsigned long long* __restrict__ cand, int* __restrict__ cnt,
                           unsigned long long* __restrict__ sel, unsigned long long* __restrict__ stash){
    int id = blockIdx.x*256 + threadIdx.x;
    if (id >= CAND_CAP) return;
    int scale, segbase;
    if (id < C26_BASE)      { scale=0; segbase=C13_BASE; }
    else if (id < C52_BASE) { scale=1; segbase=C26_BASE; }
    else                    { scale=2; segbase=C52_BASE; }
    int slot = id - segbase;
    if (slot >= cnt[scale]) return;
    unsigned long long key = cand[id];
    float s = u2f((uint32_t)(key >> 20));
    int bin = binOf(s);
    int B = cnt[9+scale];
    if (bin > B){
        int p = atomicAdd(&cnt[3+scale], 1);
        sel[scale*KPS + p] = key;
    } else if (bin == B){
        int q = atomicAdd(&cnt[6+scale], 1);
        if (q < 1024) stash[scale*1024 + q] = key;
    }
}

__global__ void __launch_bounds__(1024) k_finalize(const int* __restrict__ cnt,
                           unsigned long long* __restrict__ sel, const unsigned long long* __restrict__ stash){
    int s = blockIdx.x, t = threadIdx.x;
    __shared__ unsigned long long sk[1024];
    int sc = cnt[6+s]; if (sc > 1024) sc = 1024;
    sk[t] = (t < sc) ? stash[s*1024 + t] : 0ull;
    __syncthreads();
    for (int k=2; k<=1024; k<<=1)
        for (int j=k>>1; j>0; j>>=1){
            int ixj = t ^ j;
            if (ixj > t){
                bool up = ((t & k) == 0);   // descending overall
                unsigned long long a = sk[t], b = sk[ixj];
                if (up ? (a < b) : (a > b)){ sk[t] = b; sk[ixj] = a; }
            }
            __syncthreads();
        }
    int above = cnt[12+s];
    int need = KPS - above; if (need < 0) need = 0;
    int m = (need < sc) ? need : sc;
    if (t < m) sel[s*KPS + above + t] = sk[t];
    if (t >= above + m && t < KPS) sel[s*KPS + t] = 0ull;   // sentinels
}

__global__ void k_decode(const float* __restrict__ o13, const float* __restrict__ o26,
                         const float* __restrict__ o52,
                         const float* __restrict__ a13, const float* __restrict__ a26,
                         const float* __restrict__ a52,
                         const unsigned long long* __restrict__ sel, float* __restrict__ boxes){
    int gtid = blockIdx.x*256 + threadIdx.x;
    int b = gtid >> 6;
    int lane = threadIdx.x & 63;
    if (b >= NBOX) return;
    unsigned long long key = sel[b];
    float* row = boxes + b*12;
    if ((key >> 20) == 0ull){           // sentinel
        if (lane < 9) row[lane] = 0.f;
        return;
    }
    int scale = 2 - (int)((key >> 18) & 3ull);
    int cidx  = 262143 - (int)(key & 0x3FFFFull);
    uint32_t sbits = (uint32_t)(key >> 20);
    const float* src; const float* anch; int H; float tt;
    if (scale == 0){ src=o13; anch=a13; H=13; tt=32.f; }
    else if (scale == 1){ src=o26; anch=a26; H=26; tt=16.f; }
    else { src=o52; anch=a52; H=52; tt=8.f; }
    int HW = H*H;
    int a  = cidx % 3;
    int hw = (cidx/3) % HW;
    int n  = cidx / (3*HW);
    int hh = hw / H;
    int ww = hw - hh*H;
    const float* cellbase = src + (size_t)(n*255 + a*85)*HW + hw;
    // argmax over 80 classes, tie -> lowest class index
    float bv = cellbase[(size_t)(5 + lane)*HW];
    int bi = lane;
    if (lane < 16){
        float v2 = cellbase[(size_t)(69 + lane)*HW];
        if (v2 > bv){ bv = v2; bi = 64 + lane; }
    }
    #pragma unroll
    for (int off=32; off; off>>=1){
        float vo = __shfl_xor(bv, off);
        int io = __shfl_xor(bi, off);
        if (vo > bv || (vo == bv && io < bi)){ bv = vo; bi = io; }
    }
    if (lane == 0){
        float v1 = cellbase[(size_t)1*HW];
        float v2 = cellbase[(size_t)2*HW];
        float v3 = cellbase[(size_t)3*HW];
        float v4 = cellbase[(size_t)4*HW];
        float cx = ((float)ww + v1) * tt / 416.0f;
        float cy = ((float)hh + v2) * tt / 416.0f;
        float e3 = (float)exp((double)v3);
        float e4 = (float)exp((double)v4);
        float bw = anch[a*2+0] * e3 / 416.0f;
        float bh = anch[a*2+1] * e4 / 416.0f;
        row[0] = (float)n;  row[1] = cx; row[2] = cy; row[3] = bw; row[4] = bh;
        row[5] = u2f(sbits); row[6] = (float)bi; row[7] = (float)hh; row[8] = (float)ww;
    }
}

__global__ void __launch_bounds__(1024) k_sort(const unsigned long long* __restrict__ sel,
                       const float* __restrict__ boxes, float* __restrict__ sboxes,
                       unsigned long long* __restrict__ vwords){
    __shared__ unsigned long long sk[2048];
    int t = threadIdx.x;
    for (int r=t; r<2048; r+=1024)
        sk[r] = (r < NBOX) ? ((sel[r] << 12) | (unsigned long long)r) : 0ull;
    __syncthreads();
    for (int k=2; k<=2048; k<<=1)
        for (int j=k>>1; j>0; j>>=1){
            for (int i=t; i<2048; i+=1024){
                int ixj = i ^ j;
                if (ixj > i){
                    bool up = ((i & k) == 0);
                    unsigned long long a = sk[i], b = sk[ixj];
                    if (up ? (a < b) : (a > b)){ sk[i] = b; sk[ixj] = a; }
                }
            }
            __syncthreads();
        }
    for (int r=t; r<2048; r+=1024){
        if (r < NBOX){
            unsigned long long key = sk[r];
            bool valid = (key >> 32) != 0ull;     // top 32 bits = sigmoid bits
            int slot = (int)(key & 0xFFFull);
            #pragma unroll
            for (int c=0;c<9;c++) sboxes[r*12+c] = valid ? boxes[slot*12+c] : 0.f;
            unsigned long long ball = __ballot(valid);
            if ((r & 63) == 0) vwords[r >> 6] = ball;
        }
    }
}

__global__ void k_masks(const float* __restrict__ sboxes, unsigned long long* __restrict__ sup){
    int i = blockIdx.x;
    int lane = threadIdx.x;
    float cxi = sboxes[i*12+1], cyi = sboxes[i*12+2], wi = sboxes[i*12+3], hi = sboxes[i*12+4];
    float x1i = cxi - wi/2.0f, y1i = cyi - hi/2.0f, x2i = cxi + wi/2.0f, y2i = cyi + hi/2.0f;
    float ari = fmaxf(x2i-x1i, 0.f) * fmaxf(y2i-y1i, 0.f);
    for (int c=0; c<24; c++){
        int j = c*64 + lane;
        float cxj = sboxes[j*12+1], cyj = sboxes[j*12+2], wj = sboxes[j*12+3], hj = sboxes[j*12+4];
        float x1j = cxj - wj/2.0f, y1j = cyj - hj/2.0f, x2j = cxj + wj/2.0f, y2j = cyj + hj/2.0f;
        float arj = fmaxf(x2j-x1j, 0.f) * fmaxf(y2j-y1j, 0.f);
        float ix = fmaxf(0.f, fminf(x2i, x2j) - fmaxf(x1i, x1j));
        float iy = fmaxf(0.f, fminf(y2i, y2j) - fmaxf(y1i, y1j));
        float inter = ix * iy;
        float iou = inter / fmaxf(fminf(ari, arj), 1e-9f);
        bool sb = (iou > 0.7f) && (j > i);
        unsigned long long ball = __ballot(sb);
        if (lane == 0) sup[i*24 + c] = ball;
    }
}

__global__ void k_nms_out(const float* __restrict__ sboxes, const unsigned long long* __restrict__ vwords,
                          const unsigned long long* __restrict__ sup, float* __restrict__ out){
    __shared__ unsigned long long keepw[24];
    int t = threadIdx.x;
    if (t < 64){
        int lane = t;
        unsigned long long rem = 0ull;
        unsigned long long vwv = (lane < 24) ? vwords[lane] : 0ull;
        unsigned long long buf[8];
        #pragma unroll
        for (int d=0; d<8; d++) buf[d] = (lane < 24) ? sup[d*24 + lane] : 0ull;
        for (int g=0; g<24; g++){
            unsigned long long cur  = __shfl(rem, g);
            unsigned long long vcur = __shfl(vwv, g);
            for (int bb=0; bb<8; bb++){
                #pragma unroll
                for (int d=0; d<8; d++){
                    int b = bb*8 + d;
                    int i = (g << 6) + b;
                    unsigned long long row = buf[d];
                    int nx = i + 8;
                    buf[d] = (nx < NBOX && lane < 24) ? sup[nx*24 + lane] : 0ull;
                    bool alive = (((vcur >> b) & 1ull) != 0ull) && (((cur >> b) & 1ull) == 0ull);
                    if (alive){
                        rem |= row;
                        cur |= __shfl(row, g);
                    }
                }
            }
        }
        if (lane < 24) keepw[lane] = vwv & ~rem;
    }
    __syncthreads();
    for (int e=t; e<NBOX*9; e+=256){
        int r = e / 9;
        int c = e - r*9;
        bool kp = ((keepw[r >> 6] >> (r & 63)) & 1ull) != 0ull;
        out[e] = kp ? sboxes[r*12 + c] : 0.f;
    }
}

extern "C" void kernel_launch(void* const* d_in, const int* in_sizes, int n_in,
                              void* d_out, int out_size, void* d_ws, size_t ws_size,
                              hipStream_t stream){
    const float* o13 = (const float*)d_in[0];
    const float* o26 = (const float*)d_in[1];
    const float* o52 = (const float*)d_in[2];
    const float* a13 = (const float*)d_in[3];
    const float* a26 = (const float*)d_in[4];
    const float* a52 = (const float*)d_in[5];
    char* ws = (char*)d_ws;
    unsigned long long* cand  = (unsigned long long*)(ws);              // 344064*8 = 2,752,512
    int* hist                 = (int*)(ws + 2752512);                   // 49,152
    int* cnt                  = (int*)(ws + 2801664);                   // 256
    unsigned long long* sel   = (unsigned long long*)(ws + 2801920);    // 12,288
    unsigned long long* stash = (unsigned long long*)(ws + 2814208);    // 24,576
    float* boxes              = (float*)(ws + 2838784);                 // 73,728
    float* sboxes             = (float*)(ws + 2912512);                 // 73,728
    unsigned long long* vw    = (unsigned long long*)(ws + 2986240);    // 256
    unsigned long long* sup   = (unsigned long long*)(ws + 2986496);    // 294,912 (end ~3.28 MB)
    float* out = (float*)d_out;

    k_init    <<<48, 256, 0, stream>>>(hist, cnt);
    k_score   <<<(TOTCELL + 255)/256, 256, 0, stream>>>(o13, o26, o52, cand, cnt, hist);
    k_cutoff  <<<3, 1024, 0, stream>>>(hist, cnt);
    k_classify<<<CAND_CAP/256, 256, 0, stream>>>(cand, cnt, sel, stash);
    k_finalize<<<3, 1024, 0, stream>>>(cnt, sel, stash);
    k_decode  <<<NBOX/4, 256, 0, stream>>>(o13, o26, o52, a13, a26, a52, sel, boxes);
    k_sort    <<<1, 1024, 0, stream>>>(sel, boxes, sboxes, vw);
    k_masks   <<<NBOX, 64, 0, stream>>>(sboxes, sup);
    k_nms_out <<<1, 256, 0, stream>>>(sboxes, vw, sup, out);
}

// Round 2
// 427.691 us; speedup vs baseline: 3.9432x; 3.9432x over previous
//
#include <hip/hip_runtime.h>
#include <stdint.h>

#define KPS 512
#define NBOX 1536
#define NBINS 4096

// scale cell counts: 32*H*H*3
#define S13 16224
#define S26 64896
#define S52 259584
#define TOTCELL 340704

// candidate segment bases/caps (in keys)
#define C13_BASE 0
#define C26_BASE 16384
#define C52_BASE 81920
#define CAND_CAP 344064

__device__ __forceinline__ uint32_t f2u(float x){ union{float f;uint32_t u;}v; v.f=x; return v.u; }
__device__ __forceinline__ float u2f(uint32_t x){ union{float f;uint32_t u;}v; v.u=x; return v.f; }

__device__ __forceinline__ int binOf(float s){
    int b = (int)((s - 0.6f) * 10240.0f);
    if (b < 0) b = 0;
    if (b > NBINS-1) b = NBINS-1;
    return b;
}

// counters: [0..2] candCnt, [3..5] abovePos, [6..8] stashCnt, [9..11] cutoffB, [12..14] aboveCount
__global__ void k_init(int* hist, int* cnt){
    int id = blockIdx.x*256 + threadIdx.x;
    if (id < 3*NBINS) hist[id] = 0;
    if (id < 32) cnt[id] = 0;
}

__global__ void k_score(const float* __restrict__ o13, const float* __restrict__ o26,
                        const float* __restrict__ o52,
                        unsigned long long* __restrict__ cand, int* __restrict__ cnt,
                        int* __restrict__ hist){
    int id = blockIdx.x*256 + threadIdx.x;
    bool live = (id < TOTCELL);
    int scale=0, idl=0, H=13, segbase=0;
    const float* src = o13;
    if (live){
        if (id < S13)            { scale=0; idl=id;            H=13; src=o13; segbase=C13_BASE; }
        else if (id < S13+S26)   { scale=1; idl=id-S13;        H=26; src=o26; segbase=C26_BASE; }
        else                     { scale=2; idl=id-(S13+S26);  H=52; src=o52; segbase=C52_BASE; }
    }
    int HW = H*H;
    // plane-major thread mapping for coalescing: idl = p*HW + hw, p = n*3 + a
    int p  = idl / HW;
    int hw = idl - p*HW;
    int n  = p / 3;
    int a  = p - n*3;
    int cidx = (n*HW + hw)*3 + a;       // reference flat cell index
    float s = 0.f;
    if (live){
        float x = src[(size_t)(n*255 + a*85)*HW + hw];
        s = (float)(1.0 / (1.0 + exp(-(double)x)));   // correctly-rounded f32 sigmoid
    }
    bool pred = live && (s > 0.6f);
    int lane = threadIdx.x & 63;
    unsigned long long lanebit_m1 = (lane == 63) ? ~0ull >> 1 : ((1ull << lane) - 1ull);
    // wave-aggregated compaction per scale (waves can straddle scale boundaries)
    #pragma unroll
    for (int sc = 0; sc < 3; sc++){
        unsigned long long m = __ballot(pred && scale == sc);
        if (m){
            int leader = __ffsll((long long)m) - 1;
            int base = 0;
            if (lane == leader) base = atomicAdd(&cnt[sc], __popcll(m));
            base = __shfl(base, leader);
            if (pred && scale == sc){
                int pos = base + __popcll(m & lanebit_m1);
                unsigned long long key = ((unsigned long long)f2u(s) << 20)
                                       | ((unsigned long long)(2-scale) << 18)
                                       | (unsigned long long)(262143 - cidx);
                cand[segbase + pos] = key;
            }
        }
    }
    if (pred) atomicAdd(&hist[scale*NBINS + binOf(s)], 1);
}

__global__ void __launch_bounds__(1024) k_cutoff(const int* __restrict__ hist, int* __restrict__ cnt){
    int s = blockIdx.x, t = threadIdx.x;
    __shared__ int h[NBINS];
    __shared__ int suf[1024];
    #pragma unroll
    for (int k=0;k<4;k++) h[t*4+k] = hist[s*NBINS + t*4 + k];
    __syncthreads();
    int part = h[4*t] + h[4*t+1] + h[4*t+2] + h[4*t+3];
    suf[t] = part; __syncthreads();
    for (int d=1; d<1024; d<<=1){
        int v = (t+d < 1024) ? suf[t+d] : 0;
        __syncthreads();
        suf[t] += v;
        __syncthreads();
    }
    int total = suf[0];
    int A = (t < 1023) ? suf[t+1] : 0;
    int ca3 = A;
    int ca2 = A   + h[4*t+3];
    int ca1 = ca2 + h[4*t+2];
    int ca0 = ca1 + h[4*t+1];
    int ca[4] = {ca0, ca1, ca2, ca3};
    if (t == 0 && total < KPS){ cnt[9+s] = -1; cnt[12+s] = total; }
    #pragma unroll
    for (int k=0;k<4;k++){
        int b = 4*t + k;
        if (ca[k] < KPS && ca[k] + h[b] >= KPS){ cnt[9+s] = b; cnt[12+s] = ca[k]; }
    }
}

__global__ void k_classify(const unsigned long long* __restrict__ cand, int* __restrict__ cnt,
                           unsigned long long* __restrict__ sel, unsigned long long* __restrict__ stash){
    int id = blockIdx.x*256 + threadIdx.x;
    int scale, segbase;
    if (id < C26_BASE)      { scale=0; segbase=C13_BASE; }
    else if (id < C52_BASE) { scale=1; segbase=C26_BASE; }
    else                    { scale=2; segbase=C52_BASE; }
    int slot = id - segbase;
    bool live = (id < CAND_CAP) && (slot < cnt[scale]);
    unsigned long long key = live ? cand[id] : 0ull;
    int B = cnt[9+scale];
    int bin = live ? binOf(u2f((uint32_t)(key >> 20))) : -2;
    int lane = threadIdx.x & 63;
    unsigned long long lanebit_m1 = (lane == 63) ? ~0ull >> 1 : ((1ull << lane) - 1ull);
    bool above = live && (bin > B);
    bool bound = live && (bin == B);
    // wave-aggregate both counters (waves may straddle scales; loop scales)
    #pragma unroll
    for (int sc = 0; sc < 3; sc++){
        unsigned long long ma = __ballot(above && scale == sc);
        if (ma){
            int leader = __ffsll((long long)ma) - 1;
            int base = 0;
            if (lane == leader) base = atomicAdd(&cnt[3+sc], __popcll(ma));
            base = __shfl(base, leader);
            if (above && scale == sc)
                sel[sc*KPS + base + __popcll(ma & lanebit_m1)] = key;
        }
        unsigned long long mb = __ballot(bound && scale == sc);
        if (mb){
            int leader = __ffsll((long long)mb) - 1;
            int base = 0;
            if (lane == leader) base = atomicAdd(&cnt[6+sc], __popcll(mb));
            base = __shfl(base, leader);
            if (bound && scale == sc){
                int q = base + __popcll(mb & lanebit_m1);
                if (q < 1024) stash[sc*1024 + q] = key;
            }
        }
    }
}

__global__ void __launch_bounds__(1024) k_finalize(const int* __restrict__ cnt,
                           unsigned long long* __restrict__ sel, const unsigned long long* __restrict__ stash){
    int s = blockIdx.x, t = threadIdx.x;
    __shared__ unsigned long long sk[1024];
    int sc = cnt[6+s]; if (sc > 1024) sc = 1024;
    sk[t] = (t < sc) ? stash[s*1024 + t] : 0ull;
    __syncthreads();
    for (int k=2; k<=1024; k<<=1)
        for (int j=k>>1; j>0; j>>=1){
            int ixj = t ^ j;
            if (ixj > t){
                bool up = ((t & k) == 0);   // descending overall
                unsigned long long a = sk[t], b = sk[ixj];
                if (up ? (a < b) : (a > b)){ sk[t] = b; sk[ixj] = a; }
            }
            __syncthreads();
        }
    int above = cnt[12+s];
    int need = KPS - above; if (need < 0) need = 0;
    int m = (need < sc) ? need : sc;
    if (t < m) sel[s*KPS + above + t] = sk[t];
    if (t >= above + m && t < KPS) sel[s*KPS + t] = 0ull;   // sentinels
}

__global__ void k_decode(const float* __restrict__ o13, const float* __restrict__ o26,
                         const float* __restrict__ o52,
                         const float* __restrict__ a13, const float* __restrict__ a26,
                         const float* __restrict__ a52,
                         const unsigned long long* __restrict__ sel, float* __restrict__ boxes){
    int gtid = blockIdx.x*256 + threadIdx.x;
    int b = gtid >> 6;
    int lane = threadIdx.x & 63;
    if (b >= NBOX) return;
    unsigned long long key = sel[b];
    float* row = boxes + b*12;
    if ((key >> 20) == 0ull){           // sentinel
        if (lane < 9) row[lane] = 0.f;
        return;
    }
    int scale = 2 - (int)((key >> 18) & 3ull);
    int cidx  = 262143 - (int)(key & 0x3FFFFull);
    uint32_t sbits = (uint32_t)(key >> 20);
    const float* src; const float* anch; int H; float tt;
    if (scale == 0){ src=o13; anch=a13; H=13; tt=32.f; }
    else if (scale == 1){ src=o26; anch=a26; H=26; tt=16.f; }
    else { src=o52; anch=a52; H=52; tt=8.f; }
    int HW = H*H;
    int a  = cidx % 3;
    int hw = (cidx/3) % HW;
    int n  = cidx / (3*HW);
    int hh = hw / H;
    int ww = hw - hh*H;
    const float* cellbase = src + (size_t)(n*255 + a*85)*HW + hw;
    // argmax over 80 classes, tie -> lowest class index
    float bv = cellbase[(size_t)(5 + lane)*HW];
    int bi = lane;
    if (lane < 16){
        float v2 = cellbase[(size_t)(69 + lane)*HW];
        if (v2 > bv){ bv = v2; bi = 64 + lane; }
    }
    #pragma unroll
    for (int off=32; off; off>>=1){
        float vo = __shfl_xor(bv, off);
        int io = __shfl_xor(bi, off);
        if (vo > bv || (vo == bv && io < bi)){ bv = vo; bi = io; }
    }
    if (lane == 0){
        float v1 = cellbase[(size_t)1*HW];
        float v2 = cellbase[(size_t)2*HW];
        float v3 = cellbase[(size_t)3*HW];
        float v4 = cellbase[(size_t)4*HW];
        float cx = ((float)ww + v1) * tt / 416.0f;
        float cy = ((float)hh + v2) * tt / 416.0f;
        float e3 = (float)exp((double)v3);
        float e4 = (float)exp((double)v4);
        float bw = anch[a*2+0] * e3 / 416.0f;
        float bh = anch[a*2+1] * e4 / 416.0f;
        row[0] = (float)n;  row[1] = cx; row[2] = cy; row[3] = bw; row[4] = bh;
        row[5] = u2f(sbits); row[6] = (float)bi; row[7] = (float)hh; row[8] = (float)ww;
    }
}

__global__ void __launch_bounds__(1024) k_sort(const unsigned long long* __restrict__ sel,
                       const float* __restrict__ boxes, float* __restrict__ sboxes,
                       unsigned long long* __restrict__ vwords){
    __shared__ unsigned long long sk[2048];
    int t = threadIdx.x;
    for (int r=t; r<2048; r+=1024)
        sk[r] = (r < NBOX) ? ((sel[r] << 12) | (unsigned long long)r) : 0ull;
    __syncthreads();
    for (int k=2; k<=2048; k<<=1)
        for (int j=k>>1; j>0; j>>=1){
            for (int i=t; i<2048; i+=1024){
                int ixj = i ^ j;
                if (ixj > i){
                    bool up = ((i & k) == 0);
                    unsigned long long a = sk[i], b = sk[ixj];
                    if (up ? (a < b) : (a > b)){ sk[i] = b; sk[ixj] = a; }
                }
            }
            __syncthreads();
        }
    for (int r=t; r<2048; r+=1024){
        if (r < NBOX){
            unsigned long long key = sk[r];
            bool valid = (key >> 32) != 0ull;     // top 32 bits = sigmoid bits
            int slot = (int)(key & 0xFFFull);
            #pragma unroll
            for (int c=0;c<9;c++) sboxes[r*12+c] = valid ? boxes[slot*12+c] : 0.f;
            unsigned long long ball = __ballot(valid);
            if ((r & 63) == 0) vwords[r >> 6] = ball;
        }
    }
}

__global__ void k_masks(const float* __restrict__ sboxes, unsigned long long* __restrict__ sup){
    int i = blockIdx.x;
    int lane = threadIdx.x;
    float cxi = sboxes[i*12+1], cyi = sboxes[i*12+2], wi = sboxes[i*12+3], hi = sboxes[i*12+4];
    float x1i = cxi - wi/2.0f, y1i = cyi - hi/2.0f, x2i = cxi + wi/2.0f, y2i = cyi + hi/2.0f;
    float ari = fmaxf(x2i-x1i, 0.f) * fmaxf(y2i-y1i, 0.f);
    for (int c=0; c<24; c++){
        int j = c*64 + lane;
        float cxj = sboxes[j*12+1], cyj = sboxes[j*12+2], wj = sboxes[j*12+3], hj = sboxes[j*12+4];
        float x1j = cxj - wj/2.0f, y1j = cyj - hj/2.0f, x2j = cxj + wj/2.0f, y2j = cyj + hj/2.0f;
        float arj = fmaxf(x2j-x1j, 0.f) * fmaxf(y2j-y1j, 0.f);
        float ix = fmaxf(0.f, fminf(x2i, x2j) - fmaxf(x1i, x1j));
        float iy = fmaxf(0.f, fminf(y2i, y2j) - fmaxf(y1i, y1j));
        float inter = ix * iy;
        float iou = inter / fmaxf(fminf(ari, arj), 1e-9f);
        bool sb = (iou > 0.7f) && (j > i);
        unsigned long long ball = __ballot(sb);
        if (lane == 0) sup[i*24 + c] = ball;
    }
}

__global__ void k_nms_out(const float* __restrict__ sboxes, const unsigned long long* __restrict__ vwords,
                          const unsigned long long* __restrict__ sup, float* __restrict__ out){
    __shared__ unsigned long long keepw[24];
    int t = threadIdx.x;
    if (t < 64){
        int lane = t;
        unsigned long long rem = 0ull;
        unsigned long long vwv = (lane < 24) ? vwords[lane] : 0ull;
        unsigned long long buf[8];
        #pragma unroll
        for (int d=0; d<8; d++) buf[d] = (lane < 24) ? sup[d*24 + lane] : 0ull;
        for (int g=0; g<24; g++){
            unsigned long long cur  = __shfl(rem, g);
            unsigned long long vcur = __shfl(vwv, g);
            for (int bb=0; bb<8; bb++){
                #pragma unroll
                for (int d=0; d<8; d++){
                    int b = bb*8 + d;
                    int i = (g << 6) + b;
                    unsigned long long row = buf[d];
                    int nx = i + 8;
                    buf[d] = (nx < NBOX && lane < 24) ? sup[nx*24 + lane] : 0ull;
                    bool alive = (((vcur >> b) & 1ull) != 0ull) && (((cur >> b) & 1ull) == 0ull);
                    if (alive){
                        rem |= row;
                        cur |= __shfl(row, g);
                    }
                }
            }
        }
        if (lane < 24) keepw[lane] = vwv & ~rem;
    }
    __syncthreads();
    for (int e=t; e<NBOX*9; e+=256){
        int r = e / 9;
        int c = e - r*9;
        bool kp = ((keepw[r >> 6] >> (r & 63)) & 1ull) != 0ull;
        out[e] = kp ? sboxes[r*12 + c] : 0.f;
    }
}

extern "C" void kernel_launch(void* const* d_in, const int* in_sizes, int n_in,
                              void* d_out, int out_size, void* d_ws, size_t ws_size,
                              hipStream_t stream){
    const float* o13 = (const float*)d_in[0];
    const float* o26 = (const float*)d_in[1];
    const float* o52 = (const float*)d_in[2];
    const float* a13 = (const float*)d_in[3];
    const float* a26 = (const float*)d_in[4];
    const float* a52 = (const float*)d_in[5];
    char* ws = (char*)d_ws;
    unsigned long long* cand  = (unsigned long long*)(ws);              // 344064*8 = 2,752,512
    int* hist                 = (int*)(ws + 2752512);                   // 49,152
    int* cnt                  = (int*)(ws + 2801664);                   // 256
    unsigned long long* sel   = (unsigned long long*)(ws + 2801920);    // 12,288
    unsigned long long* stash = (unsigned long long*)(ws + 2814208);    // 24,576
    float* boxes              = (float*)(ws + 2838784);                 // 73,728
    float* sboxes             = (float*)(ws + 2912512);                 // 73,728
    unsigned long long* vw    = (unsigned long long*)(ws + 2986240);    // 256
    unsigned long long* sup   = (unsigned long long*)(ws + 2986496);    // 294,912 (end ~3.28 MB)
    float* out = (float*)d_out;

    k_init    <<<48, 256, 0, stream>>>(hist, cnt);
    k_score   <<<(TOTCELL + 255)/256, 256, 0, stream>>>(o13, o26, o52, cand, cnt, hist);
    k_cutoff  <<<3, 1024, 0, stream>>>(hist, cnt);
    k_classify<<<CAND_CAP/256, 256, 0, stream>>>(cand, cnt, sel, stash);
    k_finalize<<<3, 1024, 0, stream>>>(cnt, sel, stash);
    k_decode  <<<NBOX/4, 256, 0, stream>>>(o13, o26, o52, a13, a26, a52, sel, boxes);
    k_sort    <<<1, 1024, 0, stream>>>(sel, boxes, sboxes, vw);
    k_masks   <<<NBOX, 64, 0, stream>>>(sboxes, sup);
    k_nms_out <<<1, 256, 0, stream>>>(sboxes, vw, sup, out);
}